// Round 4
// baseline (1402.690 us; speedup 1.0000x reference)
//
#include <hip/hip_runtime.h>
#include <math.h>

#define MDIM 128
#define MY 10
#define GAMMA 0.8f
#define KITER 5

typedef float v4f __attribute__((ext_vector_type(4)));
typedef int   v2i __attribute__((ext_vector_type(2)));

__device__ __forceinline__ float bf2f(unsigned short h) {
    return __uint_as_float(((unsigned int)h) << 16);
}
__device__ __forceinline__ unsigned short f2bf(float f) {
    unsigned int u = __float_as_uint(f);
    u += 0x7fffu + ((u >> 16) & 1u);  // round-to-nearest-even
    return (unsigned short)(u >> 16);
}

// ---------------------------------------------------------------- transpose
// X [128][n] -> Y0 fp32 [n][128] and Y0h bf16 [n][128]
__global__ void k_transpose(const float* __restrict__ X, float* __restrict__ Y0,
                            unsigned short* __restrict__ Y0h, int n) {
    __shared__ float tile[32][33];
    int r0 = blockIdx.x * 32;
    int f0 = blockIdx.y * 32;
    int tx = threadIdx.x, ty = threadIdx.y;  // 32 x 8
    #pragma unroll
    for (int i = 0; i < 32; i += 8) {
        tile[ty + i][tx] = X[(size_t)(f0 + ty + i) * n + (r0 + tx)];
    }
    __syncthreads();
    #pragma unroll
    for (int i = 0; i < 32; i += 8) {
        float v = tile[tx][ty + i];
        Y0[(size_t)(r0 + ty + i) * MDIM + (f0 + tx)] = v;
        Y0h[(size_t)(r0 + ty + i) * MDIM + (f0 + tx)] = f2bf(v);
    }
}

// ---------------------------------------------------------------- Gram matrix
__global__ void k_gram(const float* __restrict__ F, float* __restrict__ FF,
                       float* __restrict__ normAcc) {
    int i = blockIdx.x, j = threadIdx.x;
    float acc = 0.f;
    for (int k = 0; k < MDIM; ++k)
        acc = fmaf(F[k * MDIM + i], F[k * MDIM + j], acc);
    FF[i * MDIM + j] = acc;
    __shared__ float red[MDIM];
    red[j] = acc * acc;
    __syncthreads();
    for (int s = 64; s > 0; s >>= 1) {
        if (j < s) red[j] += red[j + s];
        __syncthreads();
    }
    if (j == 0) atomicAdd(normAcc, red[0]);
}

__global__ void k_gnorm(const float* __restrict__ FF, const float* __restrict__ normAcc,
                        float* __restrict__ G) {
    int idx = blockIdx.x * 256 + threadIdx.x;
    float s = GAMMA / (sqrtf(*normAcc) + 1e-6f);
    G[idx] = FF[idx] * s;
}

// ---------------------------------------------------------------- CSR build
__global__ void k_hist(const int* __restrict__ erow, int* __restrict__ cnt, int E) {
    int e = blockIdx.x * 256 + threadIdx.x;
    if (e < E) atomicAdd(&cnt[erow[e]], 1);
}

__global__ void k_scan1(const int* __restrict__ cnt, int* __restrict__ blockSums, int n) {
    int tid = threadIdx.x;  // 256
    int base = blockIdx.x * 1024 + tid * 4;
    int s = 0;
    if (base + 3 < n) {
        int4 v = *(const int4*)&cnt[base];
        s = v.x + v.y + v.z + v.w;
    } else {
        for (int i = 0; i < 4; ++i)
            if (base + i < n) s += cnt[base + i];
    }
    __shared__ int red[256];
    red[tid] = s;
    __syncthreads();
    for (int st = 128; st > 0; st >>= 1) {
        if (tid < st) red[tid] += red[tid + st];
        __syncthreads();
    }
    if (tid == 0) blockSums[blockIdx.x] = red[0];
}

__global__ void k_scan2(int* __restrict__ blockSums, int* __restrict__ row_off,
                        int nb, int n) {
    __shared__ int s[256];
    int tid = threadIdx.x;  // 256
    int v = (tid < nb) ? blockSums[tid] : 0;
    s[tid] = v;
    __syncthreads();
    for (int off = 1; off < 256; off <<= 1) {
        int t = (tid >= off) ? s[tid - off] : 0;
        __syncthreads();
        s[tid] += t;
        __syncthreads();
    }
    if (tid < nb) blockSums[tid] = s[tid] - v;
    if (tid == 0) row_off[n] = s[255];
}

// phase 3: local exclusive scan + block offset; also writes cursor copy
__global__ void k_scan3(const int* __restrict__ cnt, const int* __restrict__ blockOff,
                        int* __restrict__ row_off, int* __restrict__ cursor, int n) {
    int tid = threadIdx.x;  // 256
    int base = blockIdx.x * 1024 + tid * 4;
    int v[4];
    #pragma unroll
    for (int i = 0; i < 4; ++i) v[i] = (base + i < n) ? cnt[base + i] : 0;
    int local = v[0] + v[1] + v[2] + v[3];
    __shared__ int s[256];
    s[tid] = local;
    __syncthreads();
    for (int off = 1; off < 256; off <<= 1) {
        int t = (tid >= off) ? s[tid - off] : 0;
        __syncthreads();
        s[tid] += t;
        __syncthreads();
    }
    int excl = s[tid] - local + blockOff[blockIdx.x];
    #pragma unroll
    for (int i = 0; i < 4; ++i) {
        if (base + i < n) {
            row_off[base + i] = excl;
            cursor[base + i] = excl;
            excl += v[i];
        }
    }
}

// scatter packed 8B records (col, val-bits) — single store per edge
__global__ void k_scatter(const int* __restrict__ erow, const int* __restrict__ ecol,
                          const float* __restrict__ eval_, int* __restrict__ cursor,
                          v2i* __restrict__ rec, int E) {
    int e = blockIdx.x * 256 + threadIdx.x;
    if (e < E) {
        int r = erow[e];
        int pos = atomicAdd(&cursor[r], 1);
        v2i rv;
        rv.x = ecol[e];
        rv.y = __float_as_int(eval_[e]);
        __builtin_nontemporal_store(rv, &rec[pos]);
    }
}

// ---------------------------------------------------------------- SpMM: SY = S @ Yh
// Gathers bf16 rows (256 B): 32 lanes x ushort4(8B). fp32 accumulate. Unroll x4.
// Edge stream + SY store are non-temporal: preserve L2 for Yh gathers.
__global__ void __launch_bounds__(256) k_spmm(const unsigned short* __restrict__ Yh,
                                              const int* __restrict__ row_off,
                                              const v2i* __restrict__ rec,
                                              float* __restrict__ SY, int n) {
    int row = blockIdx.x * 8 + (threadIdx.x >> 5);
    int tx = threadIdx.x & 31;
    if (row >= n) return;
    int e0 = row_off[row], e1 = row_off[row + 1];
    float4 acc = make_float4(0.f, 0.f, 0.f, 0.f);
    int e = e0;
    for (; e + 4 <= e1; e += 4) {
        v2i r0_ = __builtin_nontemporal_load(&rec[e + 0]);
        v2i r1_ = __builtin_nontemporal_load(&rec[e + 1]);
        v2i r2_ = __builtin_nontemporal_load(&rec[e + 2]);
        v2i r3_ = __builtin_nontemporal_load(&rec[e + 3]);
        ushort4 h0 = *(const ushort4*)&Yh[(size_t)r0_.x * MDIM + tx * 4];
        ushort4 h1 = *(const ushort4*)&Yh[(size_t)r1_.x * MDIM + tx * 4];
        ushort4 h2 = *(const ushort4*)&Yh[(size_t)r2_.x * MDIM + tx * 4];
        ushort4 h3 = *(const ushort4*)&Yh[(size_t)r3_.x * MDIM + tx * 4];
        float v0 = __int_as_float(r0_.y);
        float v1 = __int_as_float(r1_.y);
        float v2 = __int_as_float(r2_.y);
        float v3 = __int_as_float(r3_.y);
        acc.x = fmaf(v0, bf2f(h0.x), acc.x);
        acc.y = fmaf(v0, bf2f(h0.y), acc.y);
        acc.z = fmaf(v0, bf2f(h0.z), acc.z);
        acc.w = fmaf(v0, bf2f(h0.w), acc.w);
        acc.x = fmaf(v1, bf2f(h1.x), acc.x);
        acc.y = fmaf(v1, bf2f(h1.y), acc.y);
        acc.z = fmaf(v1, bf2f(h1.z), acc.z);
        acc.w = fmaf(v1, bf2f(h1.w), acc.w);
        acc.x = fmaf(v2, bf2f(h2.x), acc.x);
        acc.y = fmaf(v2, bf2f(h2.y), acc.y);
        acc.z = fmaf(v2, bf2f(h2.z), acc.z);
        acc.w = fmaf(v2, bf2f(h2.w), acc.w);
        acc.x = fmaf(v3, bf2f(h3.x), acc.x);
        acc.y = fmaf(v3, bf2f(h3.y), acc.y);
        acc.z = fmaf(v3, bf2f(h3.z), acc.z);
        acc.w = fmaf(v3, bf2f(h3.w), acc.w);
    }
    for (; e < e1; ++e) {
        v2i r0_ = __builtin_nontemporal_load(&rec[e]);
        float v = __int_as_float(r0_.y);
        ushort4 h = *(const ushort4*)&Yh[(size_t)r0_.x * MDIM + tx * 4];
        acc.x = fmaf(v, bf2f(h.x), acc.x);
        acc.y = fmaf(v, bf2f(h.y), acc.y);
        acc.z = fmaf(v, bf2f(h.z), acc.z);
        acc.w = fmaf(v, bf2f(h.w), acc.w);
    }
    v4f o;
    o.x = acc.x; o.y = acc.y; o.z = acc.z; o.w = acc.w;
    __builtin_nontemporal_store(o, (v4f*)&SY[(size_t)row * MDIM + tx * 4]);
}

// ---------------------------------------------------------------- dense update
// Yout = SY @ G + Y0 (fp32) and bf16 copy Yhout. Streaming traffic is nt.
__global__ void __launch_bounds__(256) k_gemm(const float* __restrict__ SY,
                                              const float* __restrict__ G,
                                              const float* __restrict__ Y0,
                                              float* __restrict__ Yout,
                                              unsigned short* __restrict__ Yhout,
                                              int writeH, int n) {
    __shared__ float sG[MDIM * MDIM];
    int tid = threadIdx.x;
    #pragma unroll
    for (int i = 0; i < 16; ++i) {
        int idx = (i * 256 + tid) * 4;
        *(float4*)&sG[idx] = *(const float4*)&G[idx];
    }
    __syncthreads();
    int tx = tid & 31, ty = tid >> 5;
    size_t r0 = (size_t)blockIdx.x * 32 + ty * 4;
    int f0 = tx * 4;
    float4 acc[4];
    #pragma unroll
    for (int i = 0; i < 4; ++i) acc[i] = make_float4(0.f, 0.f, 0.f, 0.f);
    for (int j = 0; j < MDIM; j += 4) {
        float4 g0 = *(const float4*)&sG[(j + 0) * MDIM + f0];
        float4 g1 = *(const float4*)&sG[(j + 1) * MDIM + f0];
        float4 g2 = *(const float4*)&sG[(j + 2) * MDIM + f0];
        float4 g3 = *(const float4*)&sG[(j + 3) * MDIM + f0];
        #pragma unroll
        for (int i = 0; i < 4; ++i) {
            v4f srv = __builtin_nontemporal_load((const v4f*)&SY[(r0 + i) * MDIM + j]);
            float4 sr;
            sr.x = srv.x; sr.y = srv.y; sr.z = srv.z; sr.w = srv.w;
            acc[i].x = fmaf(sr.x, g0.x, acc[i].x);
            acc[i].y = fmaf(sr.x, g0.y, acc[i].y);
            acc[i].z = fmaf(sr.x, g0.z, acc[i].z);
            acc[i].w = fmaf(sr.x, g0.w, acc[i].w);
            acc[i].x = fmaf(sr.y, g1.x, acc[i].x);
            acc[i].y = fmaf(sr.y, g1.y, acc[i].y);
            acc[i].z = fmaf(sr.y, g1.z, acc[i].z);
            acc[i].w = fmaf(sr.y, g1.w, acc[i].w);
            acc[i].x = fmaf(sr.z, g2.x, acc[i].x);
            acc[i].y = fmaf(sr.z, g2.y, acc[i].y);
            acc[i].z = fmaf(sr.z, g2.z, acc[i].z);
            acc[i].w = fmaf(sr.z, g2.w, acc[i].w);
            acc[i].x = fmaf(sr.w, g3.x, acc[i].x);
            acc[i].y = fmaf(sr.w, g3.y, acc[i].y);
            acc[i].z = fmaf(sr.w, g3.z, acc[i].z);
            acc[i].w = fmaf(sr.w, g3.w, acc[i].w);
        }
    }
    #pragma unroll
    for (int i = 0; i < 4; ++i) {
        v4f y0 = __builtin_nontemporal_load((const v4f*)&Y0[(r0 + i) * MDIM + f0]);
        v4f o;
        o.x = acc[i].x + y0.x;
        o.y = acc[i].y + y0.y;
        o.z = acc[i].z + y0.z;
        o.w = acc[i].w + y0.w;
        __builtin_nontemporal_store(o, (v4f*)&Yout[(r0 + i) * MDIM + f0]);
        if (writeH) {
            ushort4 h;
            h.x = f2bf(o.x);
            h.y = f2bf(o.y);
            h.z = f2bf(o.z);
            h.w = f2bf(o.w);
            *(ushort4*)&Yhout[(r0 + i) * MDIM + f0] = h;
        }
    }
}

// ---------------------------------------------------------------- BN stats
__global__ void k_bnstats(const float* __restrict__ Y, float* __restrict__ stats, int n) {
    int f = threadIdx.x;
    int chunk = (n + gridDim.x - 1) / gridDim.x;
    int rbeg = blockIdx.x * chunk;
    int rend = rbeg + chunk;
    if (rend > n) rend = n;
    float s = 0.f, sq = 0.f;
    for (int r = rbeg; r < rend; ++r) {
        float v = Y[(size_t)r * MDIM + f];
        s += v;
        sq = fmaf(v, v, sq);
    }
    atomicAdd(&stats[f], s);
    atomicAdd(&stats[MDIM + f], sq);
}

__global__ void k_finalize(const float* __restrict__ stats, const float* __restrict__ B,
                           const float* __restrict__ bnw, const float* __restrict__ bnb,
                           float* __restrict__ Bs, float* __restrict__ cvec, int n) {
    int f = threadIdx.x;
    float inv_n = 1.f / (float)n;
    float mu = stats[f] * inv_n;
    float var = stats[MDIM + f] * inv_n - mu * mu;
    float rs = rsqrtf(var + 1e-5f);
    float sw = rs * bnw[f];
    float cv = bnb[f] - mu * sw;
    __shared__ float red[MDIM];
    for (int o = 0; o < MY; ++o) {
        float b = B[o * MDIM + f];
        Bs[o * MDIM + f] = b * sw;
        red[f] = b * cv;
        __syncthreads();
        for (int s = 64; s > 0; s >>= 1) {
            if (f < s) red[f] += red[f + s];
            __syncthreads();
        }
        if (f == 0) cvec[o] = red[0];
        __syncthreads();
    }
}

// ---------------------------------------------------------------- projection
__global__ void __launch_bounds__(256) k_project(const float* __restrict__ Y,
                                                 const float* __restrict__ Bs,
                                                 const float* __restrict__ cvec,
                                                 float* __restrict__ out, int n) {
    __shared__ float yt[16 * 129];
    __shared__ float sB[MY * 129];
    __shared__ float sc[MY];
    int tid = threadIdx.x;
    size_t rbase = (size_t)blockIdx.x * 16;
    for (int idx = tid; idx < 16 * MDIM; idx += 256) {
        int r = idx >> 7, f = idx & 127;
        yt[r * 129 + f] = Y[(rbase + r) * MDIM + f];
    }
    for (int idx = tid; idx < MY * MDIM; idx += 256) {
        int o = idx >> 7, f = idx & 127;
        sB[o * 129 + f] = Bs[idx];
    }
    if (tid < MY) sc[tid] = cvec[tid];
    __syncthreads();
    if (tid < 16 * MY) {
        int r = tid / MY, o = tid % MY;
        float acc = sc[o];
        for (int f = 0; f < MDIM; ++f)
            acc = fmaf(yt[r * 129 + f], sB[o * 129 + f], acc);
        out[(rbase + r) * MY + o] = acc;
    }
}

// ---------------------------------------------------------------- launch
extern "C" void kernel_launch(void* const* d_in, const int* in_sizes, int n_in,
                              void* d_out, int out_size, void* d_ws, size_t ws_size,
                              hipStream_t stream) {
    const float* X    = (const float*)d_in[0];
    const float* F    = (const float*)d_in[1];
    const float* B    = (const float*)d_in[2];
    const float* bnw  = (const float*)d_in[3];
    const float* bnb  = (const float*)d_in[4];
    const float* ev   = (const float*)d_in[5];
    const int*   erow = (const int*)d_in[6];
    const int*   ecol = (const int*)d_in[7];
    float* out = (float*)d_out;
    const int n = in_sizes[0] / MDIM;  // 100000
    const int E = in_sizes[5];         // 1600000

    char* w = (char*)d_ws;
    size_t off = 0;
    auto carve = [&](size_t bytes) -> void* {
        void* p = w + off;
        off += (bytes + 255) & ~(size_t)255;
        return p;
    };
    float*          Y0    = (float*)carve((size_t)n * MDIM * 4);
    float*          Ycur  = (float*)carve((size_t)n * MDIM * 4);
    float*          SY    = (float*)carve((size_t)n * MDIM * 4);
    unsigned short* Yh    = (unsigned short*)carve((size_t)n * MDIM * 2);
    float* FF        = (float*)carve(MDIM * MDIM * 4);
    float* G         = (float*)carve(MDIM * MDIM * 4);
    v2i*   rec       = (v2i*)carve((size_t)E * 8);
    int*   row_off   = (int*)carve((size_t)(n + 1) * 4);
    int*   cursor    = (int*)carve((size_t)n * 4);
    int*   cnt       = (int*)carve((size_t)n * 4);
    int*   blockSums = (int*)carve(1024 * 4);
    float* normAcc   = (float*)carve(4);
    float* stats     = (float*)carve(2 * MDIM * 4);
    float* Bs        = (float*)carve(MY * MDIM * 4);
    float* cvec      = (float*)carve(MY * 4);
    (void)ws_size;

    hipMemsetAsync(cnt, 0, (size_t)n * 4, stream);
    hipMemsetAsync(normAcc, 0, 4, stream);
    hipMemsetAsync(stats, 0, 2 * MDIM * 4, stream);

    k_transpose<<<dim3(n / 32, MDIM / 32), dim3(32, 8), 0, stream>>>(X, Y0, Yh, n);
    k_gram<<<MDIM, MDIM, 0, stream>>>(F, FF, normAcc);
    k_gnorm<<<MDIM * MDIM / 256, 256, 0, stream>>>(FF, normAcc, G);

    const int nb = (n + 1023) / 1024;
    k_hist<<<(E + 255) / 256, 256, 0, stream>>>(erow, cnt, E);
    k_scan1<<<nb, 256, 0, stream>>>(cnt, blockSums, n);
    k_scan2<<<1, 256, 0, stream>>>(blockSums, row_off, nb, n);
    k_scan3<<<nb, 256, 0, stream>>>(cnt, blockSums, row_off, cursor, n);
    k_scatter<<<(E + 255) / 256, 256, 0, stream>>>(erow, ecol, ev, cursor, rec, E);

    for (int k = 0; k < KITER; ++k) {
        k_spmm<<<(n + 7) / 8, 256, 0, stream>>>(Yh, row_off, rec, SY, n);
        int writeH = (k < KITER - 1) ? 1 : 0;
        k_gemm<<<n / 32, 256, 0, stream>>>(SY, G, Y0, Ycur, Yh, writeH, n);
    }

    k_bnstats<<<256, MDIM, 0, stream>>>(Ycur, stats, n);
    k_finalize<<<1, MDIM, 0, stream>>>(stats, B, bnw, bnb, Bs, cvec, n);
    k_project<<<n / 16, 256, 0, stream>>>(Ycur, Bs, cvec, out, n);
}

// Round 5
// 1341.285 us; speedup vs baseline: 1.0458x; 1.0458x over previous
//
#include <hip/hip_runtime.h>
#include <math.h>

#define MDIM 128
#define MY 10
#define GAMMA 0.8f
#define KITER 5

typedef float v4f __attribute__((ext_vector_type(4)));
typedef int   v2i __attribute__((ext_vector_type(2)));

__device__ __forceinline__ float bf2f(unsigned short h) {
    return __uint_as_float(((unsigned int)h) << 16);
}
__device__ __forceinline__ unsigned short f2bf(float f) {
    unsigned int u = __float_as_uint(f);
    u += 0x7fffu + ((u >> 16) & 1u);  // round-to-nearest-even
    return (unsigned short)(u >> 16);
}

// ---------------------------------------------------------------- transpose
// X [128][n] -> Y0 fp32 [n][128] and Y0h bf16 [n][128]
__global__ void k_transpose(const float* __restrict__ X, float* __restrict__ Y0,
                            unsigned short* __restrict__ Y0h, int n) {
    __shared__ float tile[32][33];
    int r0 = blockIdx.x * 32;
    int f0 = blockIdx.y * 32;
    int tx = threadIdx.x, ty = threadIdx.y;  // 32 x 8
    #pragma unroll
    for (int i = 0; i < 32; i += 8) {
        tile[ty + i][tx] = X[(size_t)(f0 + ty + i) * n + (r0 + tx)];
    }
    __syncthreads();
    #pragma unroll
    for (int i = 0; i < 32; i += 8) {
        float v = tile[tx][ty + i];
        Y0[(size_t)(r0 + ty + i) * MDIM + (f0 + tx)] = v;
        Y0h[(size_t)(r0 + ty + i) * MDIM + (f0 + tx)] = f2bf(v);
    }
}

// ---------------------------------------------------------------- Gram matrix
__global__ void k_gram(const float* __restrict__ F, float* __restrict__ FF,
                       float* __restrict__ normAcc) {
    int i = blockIdx.x, j = threadIdx.x;
    float acc = 0.f;
    for (int k = 0; k < MDIM; ++k)
        acc = fmaf(F[k * MDIM + i], F[k * MDIM + j], acc);
    FF[i * MDIM + j] = acc;
    __shared__ float red[MDIM];
    red[j] = acc * acc;
    __syncthreads();
    for (int s = 64; s > 0; s >>= 1) {
        if (j < s) red[j] += red[j + s];
        __syncthreads();
    }
    if (j == 0) atomicAdd(normAcc, red[0]);
}

__global__ void k_gnorm(const float* __restrict__ FF, const float* __restrict__ normAcc,
                        float* __restrict__ G) {
    int idx = blockIdx.x * 256 + threadIdx.x;
    float s = GAMMA / (sqrtf(*normAcc) + 1e-6f);
    G[idx] = FF[idx] * s;
}

// ---------------------------------------------------------------- CSR build
__global__ void k_hist(const int* __restrict__ erow, int* __restrict__ cnt, int E) {
    int e = blockIdx.x * 256 + threadIdx.x;
    if (e < E) atomicAdd(&cnt[erow[e]], 1);
}

__global__ void k_scan1(const int* __restrict__ cnt, int* __restrict__ blockSums, int n) {
    int tid = threadIdx.x;  // 256
    int base = blockIdx.x * 1024 + tid * 4;
    int s = 0;
    if (base + 3 < n) {
        int4 v = *(const int4*)&cnt[base];
        s = v.x + v.y + v.z + v.w;
    } else {
        for (int i = 0; i < 4; ++i)
            if (base + i < n) s += cnt[base + i];
    }
    __shared__ int red[256];
    red[tid] = s;
    __syncthreads();
    for (int st = 128; st > 0; st >>= 1) {
        if (tid < st) red[tid] += red[tid + st];
        __syncthreads();
    }
    if (tid == 0) blockSums[blockIdx.x] = red[0];
}

__global__ void k_scan2(int* __restrict__ blockSums, int* __restrict__ row_off,
                        int nb, int n) {
    __shared__ int s[256];
    int tid = threadIdx.x;  // 256
    int v = (tid < nb) ? blockSums[tid] : 0;
    s[tid] = v;
    __syncthreads();
    for (int off = 1; off < 256; off <<= 1) {
        int t = (tid >= off) ? s[tid - off] : 0;
        __syncthreads();
        s[tid] += t;
        __syncthreads();
    }
    if (tid < nb) blockSums[tid] = s[tid] - v;
    if (tid == 0) row_off[n] = s[255];
}

__global__ void k_scan3(const int* __restrict__ cnt, const int* __restrict__ blockOff,
                        int* __restrict__ row_off, int* __restrict__ cursor, int n) {
    int tid = threadIdx.x;  // 256
    int base = blockIdx.x * 1024 + tid * 4;
    int v[4];
    #pragma unroll
    for (int i = 0; i < 4; ++i) v[i] = (base + i < n) ? cnt[base + i] : 0;
    int local = v[0] + v[1] + v[2] + v[3];
    __shared__ int s[256];
    s[tid] = local;
    __syncthreads();
    for (int off = 1; off < 256; off <<= 1) {
        int t = (tid >= off) ? s[tid - off] : 0;
        __syncthreads();
        s[tid] += t;
        __syncthreads();
    }
    int excl = s[tid] - local + blockOff[blockIdx.x];
    #pragma unroll
    for (int i = 0; i < 4; ++i) {
        if (base + i < n) {
            row_off[base + i] = excl;
            cursor[base + i] = excl;
            excl += v[i];
        }
    }
}

// scatter packed 8B records (col, val-bits) — single nt store per edge
__global__ void k_scatter(const int* __restrict__ erow, const int* __restrict__ ecol,
                          const float* __restrict__ eval_, int* __restrict__ cursor,
                          v2i* __restrict__ rec, int E) {
    int e = blockIdx.x * 256 + threadIdx.x;
    if (e < E) {
        int r = erow[e];
        int pos = atomicAdd(&cursor[r], 1);
        v2i rv;
        rv.x = ecol[e];
        rv.y = __float_as_int(eval_[e]);
        __builtin_nontemporal_store(rv, &rec[pos]);
    }
}

// ---------------------------------------------------------------- SpMM: SY = S @ Yh
// Gathers bf16 rows (256 B): 32 lanes x ushort4(8B). fp32 accumulate. Unroll x4.
// Only the edge-record stream is nt (stream-once); SY store stays cached (L2 reuse
// by the following gemm — R4 showed nt here costs ~300 us globally).
__global__ void __launch_bounds__(256) k_spmm(const unsigned short* __restrict__ Yh,
                                              const int* __restrict__ row_off,
                                              const v2i* __restrict__ rec,
                                              float* __restrict__ SY, int n) {
    int row = blockIdx.x * 8 + (threadIdx.x >> 5);
    int tx = threadIdx.x & 31;
    if (row >= n) return;
    int e0 = row_off[row], e1 = row_off[row + 1];
    float4 acc = make_float4(0.f, 0.f, 0.f, 0.f);
    int e = e0;
    for (; e + 4 <= e1; e += 4) {
        v2i r0_ = __builtin_nontemporal_load(&rec[e + 0]);
        v2i r1_ = __builtin_nontemporal_load(&rec[e + 1]);
        v2i r2_ = __builtin_nontemporal_load(&rec[e + 2]);
        v2i r3_ = __builtin_nontemporal_load(&rec[e + 3]);
        ushort4 h0 = *(const ushort4*)&Yh[(size_t)r0_.x * MDIM + tx * 4];
        ushort4 h1 = *(const ushort4*)&Yh[(size_t)r1_.x * MDIM + tx * 4];
        ushort4 h2 = *(const ushort4*)&Yh[(size_t)r2_.x * MDIM + tx * 4];
        ushort4 h3 = *(const ushort4*)&Yh[(size_t)r3_.x * MDIM + tx * 4];
        float v0 = __int_as_float(r0_.y);
        float v1 = __int_as_float(r1_.y);
        float v2 = __int_as_float(r2_.y);
        float v3 = __int_as_float(r3_.y);
        acc.x = fmaf(v0, bf2f(h0.x), acc.x);
        acc.y = fmaf(v0, bf2f(h0.y), acc.y);
        acc.z = fmaf(v0, bf2f(h0.z), acc.z);
        acc.w = fmaf(v0, bf2f(h0.w), acc.w);
        acc.x = fmaf(v1, bf2f(h1.x), acc.x);
        acc.y = fmaf(v1, bf2f(h1.y), acc.y);
        acc.z = fmaf(v1, bf2f(h1.z), acc.z);
        acc.w = fmaf(v1, bf2f(h1.w), acc.w);
        acc.x = fmaf(v2, bf2f(h2.x), acc.x);
        acc.y = fmaf(v2, bf2f(h2.y), acc.y);
        acc.z = fmaf(v2, bf2f(h2.z), acc.z);
        acc.w = fmaf(v2, bf2f(h2.w), acc.w);
        acc.x = fmaf(v3, bf2f(h3.x), acc.x);
        acc.y = fmaf(v3, bf2f(h3.y), acc.y);
        acc.z = fmaf(v3, bf2f(h3.z), acc.z);
        acc.w = fmaf(v3, bf2f(h3.w), acc.w);
    }
    for (; e < e1; ++e) {
        v2i r0_ = __builtin_nontemporal_load(&rec[e]);
        float v = __int_as_float(r0_.y);
        ushort4 h = *(const ushort4*)&Yh[(size_t)r0_.x * MDIM + tx * 4];
        acc.x = fmaf(v, bf2f(h.x), acc.x);
        acc.y = fmaf(v, bf2f(h.y), acc.y);
        acc.z = fmaf(v, bf2f(h.z), acc.z);
        acc.w = fmaf(v, bf2f(h.w), acc.w);
    }
    *(float4*)&SY[(size_t)row * MDIM + tx * 4] = acc;
}

// ---------------------------------------------------------------- dense update
// Yout = SY @ G + Y0; optional bf16 copy; optional fused BN-stat accumulation
// (doStats on the LAST iteration only: per-feature sum/sumsq block-reduced in
//  LDS then one atomicAdd per feature per block — kills the k_bnstats kernel).
__global__ void __launch_bounds__(256) k_gemm(const float* __restrict__ SY,
                                              const float* __restrict__ G,
                                              const float* __restrict__ Y0,
                                              float* __restrict__ Yout,
                                              unsigned short* __restrict__ Yhout,
                                              float* __restrict__ stats,
                                              int writeH, int doStats, int n) {
    __shared__ float sG[MDIM * MDIM];
    __shared__ float sSum[8][MDIM];
    __shared__ float sSq[8][MDIM];
    int tid = threadIdx.x;
    #pragma unroll
    for (int i = 0; i < 16; ++i) {
        int idx = (i * 256 + tid) * 4;
        *(float4*)&sG[idx] = *(const float4*)&G[idx];
    }
    __syncthreads();
    int tx = tid & 31, ty = tid >> 5;
    size_t r0 = (size_t)blockIdx.x * 32 + ty * 4;
    int f0 = tx * 4;
    float4 acc[4];
    #pragma unroll
    for (int i = 0; i < 4; ++i) acc[i] = make_float4(0.f, 0.f, 0.f, 0.f);
    for (int j = 0; j < MDIM; j += 4) {
        float4 g0 = *(const float4*)&sG[(j + 0) * MDIM + f0];
        float4 g1 = *(const float4*)&sG[(j + 1) * MDIM + f0];
        float4 g2 = *(const float4*)&sG[(j + 2) * MDIM + f0];
        float4 g3 = *(const float4*)&sG[(j + 3) * MDIM + f0];
        #pragma unroll
        for (int i = 0; i < 4; ++i) {
            float4 sr = *(const float4*)&SY[(r0 + i) * MDIM + j];
            acc[i].x = fmaf(sr.x, g0.x, acc[i].x);
            acc[i].y = fmaf(sr.x, g0.y, acc[i].y);
            acc[i].z = fmaf(sr.x, g0.z, acc[i].z);
            acc[i].w = fmaf(sr.x, g0.w, acc[i].w);
            acc[i].x = fmaf(sr.y, g1.x, acc[i].x);
            acc[i].y = fmaf(sr.y, g1.y, acc[i].y);
            acc[i].z = fmaf(sr.y, g1.z, acc[i].z);
            acc[i].w = fmaf(sr.y, g1.w, acc[i].w);
            acc[i].x = fmaf(sr.z, g2.x, acc[i].x);
            acc[i].y = fmaf(sr.z, g2.y, acc[i].y);
            acc[i].z = fmaf(sr.z, g2.z, acc[i].z);
            acc[i].w = fmaf(sr.z, g2.w, acc[i].w);
            acc[i].x = fmaf(sr.w, g3.x, acc[i].x);
            acc[i].y = fmaf(sr.w, g3.y, acc[i].y);
            acc[i].z = fmaf(sr.w, g3.z, acc[i].z);
            acc[i].w = fmaf(sr.w, g3.w, acc[i].w);
        }
    }
    float4 fsum = make_float4(0.f, 0.f, 0.f, 0.f);
    float4 fsq  = make_float4(0.f, 0.f, 0.f, 0.f);
    #pragma unroll
    for (int i = 0; i < 4; ++i) {
        float4 y0 = *(const float4*)&Y0[(r0 + i) * MDIM + f0];
        float4 o;
        o.x = acc[i].x + y0.x;
        o.y = acc[i].y + y0.y;
        o.z = acc[i].z + y0.z;
        o.w = acc[i].w + y0.w;
        *(float4*)&Yout[(r0 + i) * MDIM + f0] = o;
        if (writeH) {
            ushort4 h;
            h.x = f2bf(o.x);
            h.y = f2bf(o.y);
            h.z = f2bf(o.z);
            h.w = f2bf(o.w);
            *(ushort4*)&Yhout[(r0 + i) * MDIM + f0] = h;
        }
        if (doStats) {
            fsum.x += o.x; fsum.y += o.y; fsum.z += o.z; fsum.w += o.w;
            fsq.x = fmaf(o.x, o.x, fsq.x);
            fsq.y = fmaf(o.y, o.y, fsq.y);
            fsq.z = fmaf(o.z, o.z, fsq.z);
            fsq.w = fmaf(o.w, o.w, fsq.w);
        }
    }
    if (doStats) {
        *(float4*)&sSum[ty][f0] = fsum;
        *(float4*)&sSq[ty][f0]  = fsq;
        __syncthreads();
        if (ty == 0) {
            float4 ts = fsum, tq = fsq;
            #pragma unroll
            for (int t = 1; t < 8; ++t) {
                float4 a = *(const float4*)&sSum[t][f0];
                float4 b = *(const float4*)&sSq[t][f0];
                ts.x += a.x; ts.y += a.y; ts.z += a.z; ts.w += a.w;
                tq.x += b.x; tq.y += b.y; tq.z += b.z; tq.w += b.w;
            }
            atomicAdd(&stats[f0 + 0], ts.x);
            atomicAdd(&stats[f0 + 1], ts.y);
            atomicAdd(&stats[f0 + 2], ts.z);
            atomicAdd(&stats[f0 + 3], ts.w);
            atomicAdd(&stats[MDIM + f0 + 0], tq.x);
            atomicAdd(&stats[MDIM + f0 + 1], tq.y);
            atomicAdd(&stats[MDIM + f0 + 2], tq.z);
            atomicAdd(&stats[MDIM + f0 + 3], tq.w);
        }
    }
}

__global__ void k_finalize(const float* __restrict__ stats, const float* __restrict__ B,
                           const float* __restrict__ bnw, const float* __restrict__ bnb,
                           float* __restrict__ Bs, float* __restrict__ cvec, int n) {
    int f = threadIdx.x;
    float inv_n = 1.f / (float)n;
    float mu = stats[f] * inv_n;
    float var = stats[MDIM + f] * inv_n - mu * mu;
    float rs = rsqrtf(var + 1e-5f);
    float sw = rs * bnw[f];
    float cv = bnb[f] - mu * sw;
    __shared__ float red[MDIM];
    for (int o = 0; o < MY; ++o) {
        float b = B[o * MDIM + f];
        Bs[o * MDIM + f] = b * sw;
        red[f] = b * cv;
        __syncthreads();
        for (int s = 64; s > 0; s >>= 1) {
            if (f < s) red[f] += red[f + s];
            __syncthreads();
        }
        if (f == 0) cvec[o] = red[0];
        __syncthreads();
    }
}

// ---------------------------------------------------------------- projection
__global__ void __launch_bounds__(256) k_project(const float* __restrict__ Y,
                                                 const float* __restrict__ Bs,
                                                 const float* __restrict__ cvec,
                                                 float* __restrict__ out, int n) {
    __shared__ float yt[16 * 129];
    __shared__ float sB[MY * 129];
    __shared__ float sc[MY];
    int tid = threadIdx.x;
    size_t rbase = (size_t)blockIdx.x * 16;
    for (int idx = tid; idx < 16 * MDIM; idx += 256) {
        int r = idx >> 7, f = idx & 127;
        yt[r * 129 + f] = Y[(rbase + r) * MDIM + f];
    }
    for (int idx = tid; idx < MY * MDIM; idx += 256) {
        int o = idx >> 7, f = idx & 127;
        sB[o * 129 + f] = Bs[idx];
    }
    if (tid < MY) sc[tid] = cvec[tid];
    __syncthreads();
    if (tid < 16 * MY) {
        int r = tid / MY, o = tid % MY;
        float acc = sc[o];
        for (int f = 0; f < MDIM; ++f)
            acc = fmaf(yt[r * 129 + f], sB[o * 129 + f], acc);
        out[(rbase + r) * MY + o] = acc;
    }
}

// ---------------------------------------------------------------- launch
extern "C" void kernel_launch(void* const* d_in, const int* in_sizes, int n_in,
                              void* d_out, int out_size, void* d_ws, size_t ws_size,
                              hipStream_t stream) {
    const float* X    = (const float*)d_in[0];
    const float* F    = (const float*)d_in[1];
    const float* B    = (const float*)d_in[2];
    const float* bnw  = (const float*)d_in[3];
    const float* bnb  = (const float*)d_in[4];
    const float* ev   = (const float*)d_in[5];
    const int*   erow = (const int*)d_in[6];
    const int*   ecol = (const int*)d_in[7];
    float* out = (float*)d_out;
    const int n = in_sizes[0] / MDIM;  // 100000
    const int E = in_sizes[5];         // 1600000

    char* w = (char*)d_ws;
    size_t off = 0;
    auto carve = [&](size_t bytes) -> void* {
        void* p = w + off;
        off += (bytes + 255) & ~(size_t)255;
        return p;
    };
    float*          Y0    = (float*)carve((size_t)n * MDIM * 4);
    float*          Ycur  = (float*)carve((size_t)n * MDIM * 4);
    float*          SY    = (float*)carve((size_t)n * MDIM * 4);
    unsigned short* Yh    = (unsigned short*)carve((size_t)n * MDIM * 2);
    float* FF        = (float*)carve(MDIM * MDIM * 4);
    float* G         = (float*)carve(MDIM * MDIM * 4);
    v2i*   rec       = (v2i*)carve((size_t)E * 8);
    int*   row_off   = (int*)carve((size_t)(n + 1) * 4);
    int*   cursor    = (int*)carve((size_t)n * 4);
    int*   cnt       = (int*)carve((size_t)n * 4);
    int*   blockSums = (int*)carve(1024 * 4);
    float* normAcc   = (float*)carve(4);
    float* stats     = (float*)carve(2 * MDIM * 4);
    float* Bs        = (float*)carve(MY * MDIM * 4);
    float* cvec      = (float*)carve(MY * 4);
    (void)ws_size;

    hipMemsetAsync(cnt, 0, (size_t)n * 4, stream);
    hipMemsetAsync(normAcc, 0, 4, stream);
    hipMemsetAsync(stats, 0, 2 * MDIM * 4, stream);

    k_transpose<<<dim3(n / 32, MDIM / 32), dim3(32, 8), 0, stream>>>(X, Y0, Yh, n);
    k_gram<<<MDIM, MDIM, 0, stream>>>(F, FF, normAcc);
    k_gnorm<<<MDIM * MDIM / 256, 256, 0, stream>>>(FF, normAcc, G);

    const int nb = (n + 1023) / 1024;
    k_hist<<<(E + 255) / 256, 256, 0, stream>>>(erow, cnt, E);
    k_scan1<<<nb, 256, 0, stream>>>(cnt, blockSums, n);
    k_scan2<<<1, 256, 0, stream>>>(blockSums, row_off, nb, n);
    k_scan3<<<nb, 256, 0, stream>>>(cnt, blockSums, row_off, cursor, n);
    k_scatter<<<(E + 255) / 256, 256, 0, stream>>>(erow, ecol, ev, cursor, rec, E);

    for (int k = 0; k < KITER; ++k) {
        k_spmm<<<(n + 7) / 8, 256, 0, stream>>>(Yh, row_off, rec, SY, n);
        int writeH = (k < KITER - 1) ? 1 : 0;
        int doStats = (k == KITER - 1) ? 1 : 0;
        k_gemm<<<n / 32, 256, 0, stream>>>(SY, G, Y0, Ycur, Yh, stats, writeH, doStats, n);
    }

    k_finalize<<<1, MDIM, 0, stream>>>(stats, B, bnw, bnb, Bs, cvec, n);
    k_project<<<n / 16, 256, 0, stream>>>(Ycur, Bs, cvec, out, n);
}

// Round 6
// 1308.001 us; speedup vs baseline: 1.0724x; 1.0254x over previous
//
#include <hip/hip_runtime.h>
#include <math.h>

#define MDIM 128
#define MY 10
#define GAMMA 0.8f
#define KITER 5

typedef float v4f __attribute__((ext_vector_type(4)));
typedef int   v2i __attribute__((ext_vector_type(2)));

__device__ __forceinline__ float bf2f(unsigned short h) {
    return __uint_as_float(((unsigned int)h) << 16);
}
__device__ __forceinline__ unsigned short f2bf(float f) {
    unsigned int u = __float_as_uint(f);
    u += 0x7fffu + ((u >> 16) & 1u);  // round-to-nearest-even
    return (unsigned short)(u >> 16);
}

// ---------------------------------------------------------------- transpose
// X [128][n] -> Y0 fp32 [n][128] and Y0h bf16 [n][128]
__global__ void k_transpose(const float* __restrict__ X, float* __restrict__ Y0,
                            unsigned short* __restrict__ Y0h, int n) {
    __shared__ float tile[32][33];
    int r0 = blockIdx.x * 32;
    int f0 = blockIdx.y * 32;
    int tx = threadIdx.x, ty = threadIdx.y;  // 32 x 8
    #pragma unroll
    for (int i = 0; i < 32; i += 8) {
        tile[ty + i][tx] = X[(size_t)(f0 + ty + i) * n + (r0 + tx)];
    }
    __syncthreads();
    #pragma unroll
    for (int i = 0; i < 32; i += 8) {
        float v = tile[tx][ty + i];
        Y0[(size_t)(r0 + ty + i) * MDIM + (f0 + tx)] = v;
        Y0h[(size_t)(r0 + ty + i) * MDIM + (f0 + tx)] = f2bf(v);
    }
}

// ---------------------------------------------------------------- Gram matrix
__global__ void k_gram(const float* __restrict__ F, float* __restrict__ FF,
                       float* __restrict__ normAcc) {
    int i = blockIdx.x, j = threadIdx.x;
    float acc = 0.f;
    for (int k = 0; k < MDIM; ++k)
        acc = fmaf(F[k * MDIM + i], F[k * MDIM + j], acc);
    FF[i * MDIM + j] = acc;
    __shared__ float red[MDIM];
    red[j] = acc * acc;
    __syncthreads();
    for (int s = 64; s > 0; s >>= 1) {
        if (j < s) red[j] += red[j + s];
        __syncthreads();
    }
    if (j == 0) atomicAdd(normAcc, red[0]);
}

__global__ void k_gnorm(const float* __restrict__ FF, const float* __restrict__ normAcc,
                        float* __restrict__ G) {
    int idx = blockIdx.x * 256 + threadIdx.x;
    float s = GAMMA / (sqrtf(*normAcc) + 1e-6f);
    G[idx] = FF[idx] * s;
}

// ---------------------------------------------------------------- CSR build
__global__ void k_hist(const int* __restrict__ erow, int* __restrict__ cnt, int E) {
    int e = blockIdx.x * 256 + threadIdx.x;
    if (e < E) atomicAdd(&cnt[erow[e]], 1);
}

__global__ void k_scan1(const int* __restrict__ cnt, int* __restrict__ blockSums, int n) {
    int tid = threadIdx.x;  // 256
    int base = blockIdx.x * 1024 + tid * 4;
    int s = 0;
    if (base + 3 < n) {
        int4 v = *(const int4*)&cnt[base];
        s = v.x + v.y + v.z + v.w;
    } else {
        for (int i = 0; i < 4; ++i)
            if (base + i < n) s += cnt[base + i];
    }
    __shared__ int red[256];
    red[tid] = s;
    __syncthreads();
    for (int st = 128; st > 0; st >>= 1) {
        if (tid < st) red[tid] += red[tid + st];
        __syncthreads();
    }
    if (tid == 0) blockSums[blockIdx.x] = red[0];
}

__global__ void k_scan2(int* __restrict__ blockSums, int* __restrict__ row_off,
                        int nb, int n) {
    __shared__ int s[256];
    int tid = threadIdx.x;  // 256
    int v = (tid < nb) ? blockSums[tid] : 0;
    s[tid] = v;
    __syncthreads();
    for (int off = 1; off < 256; off <<= 1) {
        int t = (tid >= off) ? s[tid - off] : 0;
        __syncthreads();
        s[tid] += t;
        __syncthreads();
    }
    if (tid < nb) blockSums[tid] = s[tid] - v;
    if (tid == 0) row_off[n] = s[255];
}

__global__ void k_scan3(const int* __restrict__ cnt, const int* __restrict__ blockOff,
                        int* __restrict__ row_off, int* __restrict__ cursor, int n) {
    int tid = threadIdx.x;  // 256
    int base = blockIdx.x * 1024 + tid * 4;
    int v[4];
    #pragma unroll
    for (int i = 0; i < 4; ++i) v[i] = (base + i < n) ? cnt[base + i] : 0;
    int local = v[0] + v[1] + v[2] + v[3];
    __shared__ int s[256];
    s[tid] = local;
    __syncthreads();
    for (int off = 1; off < 256; off <<= 1) {
        int t = (tid >= off) ? s[tid - off] : 0;
        __syncthreads();
        s[tid] += t;
        __syncthreads();
    }
    int excl = s[tid] - local + blockOff[blockIdx.x];
    #pragma unroll
    for (int i = 0; i < 4; ++i) {
        if (base + i < n) {
            row_off[base + i] = excl;
            cursor[base + i] = excl;
            excl += v[i];
        }
    }
}

// scatter packed 8B records (col, val-bits) — single nt store per edge
__global__ void k_scatter(const int* __restrict__ erow, const int* __restrict__ ecol,
                          const float* __restrict__ eval_, int* __restrict__ cursor,
                          v2i* __restrict__ rec, int E) {
    int e = blockIdx.x * 256 + threadIdx.x;
    if (e < E) {
        int r = erow[e];
        int pos = atomicAdd(&cursor[r], 1);
        v2i rv;
        rv.x = ecol[e];
        rv.y = __float_as_int(eval_[e]);
        __builtin_nontemporal_store(rv, &rec[pos]);
    }
}

// ---------------------------------------------------------------- SpMM: SY = S @ Yh
// Gathers bf16 rows (256 B): 32 lanes x ushort4(8B). fp32 accumulate. Unroll x4.
// Only the edge-record stream is nt (stream-once); all state stays cached.
__global__ void __launch_bounds__(256) k_spmm(const unsigned short* __restrict__ Yh,
                                              const int* __restrict__ row_off,
                                              const v2i* __restrict__ rec,
                                              float* __restrict__ SY, int n) {
    int row = blockIdx.x * 8 + (threadIdx.x >> 5);
    int tx = threadIdx.x & 31;
    if (row >= n) return;
    int e0 = row_off[row], e1 = row_off[row + 1];
    float4 acc = make_float4(0.f, 0.f, 0.f, 0.f);
    int e = e0;
    for (; e + 4 <= e1; e += 4) {
        v2i r0_ = __builtin_nontemporal_load(&rec[e + 0]);
        v2i r1_ = __builtin_nontemporal_load(&rec[e + 1]);
        v2i r2_ = __builtin_nontemporal_load(&rec[e + 2]);
        v2i r3_ = __builtin_nontemporal_load(&rec[e + 3]);
        ushort4 h0 = *(const ushort4*)&Yh[(size_t)r0_.x * MDIM + tx * 4];
        ushort4 h1 = *(const ushort4*)&Yh[(size_t)r1_.x * MDIM + tx * 4];
        ushort4 h2 = *(const ushort4*)&Yh[(size_t)r2_.x * MDIM + tx * 4];
        ushort4 h3 = *(const ushort4*)&Yh[(size_t)r3_.x * MDIM + tx * 4];
        float v0 = __int_as_float(r0_.y);
        float v1 = __int_as_float(r1_.y);
        float v2 = __int_as_float(r2_.y);
        float v3 = __int_as_float(r3_.y);
        acc.x = fmaf(v0, bf2f(h0.x), acc.x);
        acc.y = fmaf(v0, bf2f(h0.y), acc.y);
        acc.z = fmaf(v0, bf2f(h0.z), acc.z);
        acc.w = fmaf(v0, bf2f(h0.w), acc.w);
        acc.x = fmaf(v1, bf2f(h1.x), acc.x);
        acc.y = fmaf(v1, bf2f(h1.y), acc.y);
        acc.z = fmaf(v1, bf2f(h1.z), acc.z);
        acc.w = fmaf(v1, bf2f(h1.w), acc.w);
        acc.x = fmaf(v2, bf2f(h2.x), acc.x);
        acc.y = fmaf(v2, bf2f(h2.y), acc.y);
        acc.z = fmaf(v2, bf2f(h2.z), acc.z);
        acc.w = fmaf(v2, bf2f(h2.w), acc.w);
        acc.x = fmaf(v3, bf2f(h3.x), acc.x);
        acc.y = fmaf(v3, bf2f(h3.y), acc.y);
        acc.z = fmaf(v3, bf2f(h3.z), acc.z);
        acc.w = fmaf(v3, bf2f(h3.w), acc.w);
    }
    for (; e < e1; ++e) {
        v2i r0_ = __builtin_nontemporal_load(&rec[e]);
        float v = __int_as_float(r0_.y);
        ushort4 h = *(const ushort4*)&Yh[(size_t)r0_.x * MDIM + tx * 4];
        acc.x = fmaf(v, bf2f(h.x), acc.x);
        acc.y = fmaf(v, bf2f(h.y), acc.y);
        acc.z = fmaf(v, bf2f(h.z), acc.z);
        acc.w = fmaf(v, bf2f(h.w), acc.w);
    }
    *(float4*)&SY[(size_t)row * MDIM + tx * 4] = acc;
}

// ---------------------------------------------------------------- dense update
// Yout = SY @ G + Y0; optional bf16 copy; optional fused BN stats.
// LDS = 32 KB: G staged in TWO 64-row halves (load/sync/compute/sync).
// R5 lesson: 72 KB LDS -> 1 block/CU -> 316 us latency-bound. 32 KB -> ~5 blocks/CU.
// Stats reduction reuses the dead sG space after the last barrier.
__global__ void __launch_bounds__(256) k_gemm(const float* __restrict__ SY,
                                              const float* __restrict__ G,
                                              const float* __restrict__ Y0,
                                              float* __restrict__ Yout,
                                              unsigned short* __restrict__ Yhout,
                                              float* __restrict__ stats,
                                              int writeH, int doStats, int n) {
    __shared__ float sG[64 * MDIM];  // 32 KB
    int tid = threadIdx.x;
    int tx = tid & 31, ty = tid >> 5;
    size_t r0 = (size_t)blockIdx.x * 32 + ty * 4;
    int f0 = tx * 4;
    float4 acc[4];
    #pragma unroll
    for (int i = 0; i < 4; ++i) acc[i] = make_float4(0.f, 0.f, 0.f, 0.f);

    #pragma unroll
    for (int half = 0; half < 2; ++half) {
        if (half) __syncthreads();  // previous half's reads must finish before overwrite
        #pragma unroll
        for (int i = 0; i < 8; ++i) {
            int idx = (i * 256 + tid) * 4;
            *(float4*)&sG[idx] = *(const float4*)&G[half * 64 * MDIM + idx];
        }
        __syncthreads();
        int kbase = half * 64;
        for (int j = 0; j < 64; j += 4) {
            float4 g0 = *(const float4*)&sG[(j + 0) * MDIM + f0];
            float4 g1 = *(const float4*)&sG[(j + 1) * MDIM + f0];
            float4 g2 = *(const float4*)&sG[(j + 2) * MDIM + f0];
            float4 g3 = *(const float4*)&sG[(j + 3) * MDIM + f0];
            #pragma unroll
            for (int i = 0; i < 4; ++i) {
                float4 sr = *(const float4*)&SY[(r0 + i) * MDIM + kbase + j];
                acc[i].x = fmaf(sr.x, g0.x, acc[i].x);
                acc[i].y = fmaf(sr.x, g0.y, acc[i].y);
                acc[i].z = fmaf(sr.x, g0.z, acc[i].z);
                acc[i].w = fmaf(sr.x, g0.w, acc[i].w);
                acc[i].x = fmaf(sr.y, g1.x, acc[i].x);
                acc[i].y = fmaf(sr.y, g1.y, acc[i].y);
                acc[i].z = fmaf(sr.y, g1.z, acc[i].z);
                acc[i].w = fmaf(sr.y, g1.w, acc[i].w);
                acc[i].x = fmaf(sr.z, g2.x, acc[i].x);
                acc[i].y = fmaf(sr.z, g2.y, acc[i].y);
                acc[i].z = fmaf(sr.z, g2.z, acc[i].z);
                acc[i].w = fmaf(sr.z, g2.w, acc[i].w);
                acc[i].x = fmaf(sr.w, g3.x, acc[i].x);
                acc[i].y = fmaf(sr.w, g3.y, acc[i].y);
                acc[i].z = fmaf(sr.w, g3.z, acc[i].z);
                acc[i].w = fmaf(sr.w, g3.w, acc[i].w);
            }
        }
    }
    __syncthreads();  // all sG reads done — safe to reuse sG for stats below

    float4 fsum = make_float4(0.f, 0.f, 0.f, 0.f);
    float4 fsq  = make_float4(0.f, 0.f, 0.f, 0.f);
    #pragma unroll
    for (int i = 0; i < 4; ++i) {
        float4 y0 = *(const float4*)&Y0[(r0 + i) * MDIM + f0];
        float4 o;
        o.x = acc[i].x + y0.x;
        o.y = acc[i].y + y0.y;
        o.z = acc[i].z + y0.z;
        o.w = acc[i].w + y0.w;
        *(float4*)&Yout[(r0 + i) * MDIM + f0] = o;
        if (writeH) {
            ushort4 h;
            h.x = f2bf(o.x);
            h.y = f2bf(o.y);
            h.z = f2bf(o.z);
            h.w = f2bf(o.w);
            *(ushort4*)&Yhout[(r0 + i) * MDIM + f0] = h;
        }
        if (doStats) {
            fsum.x += o.x; fsum.y += o.y; fsum.z += o.z; fsum.w += o.w;
            fsq.x = fmaf(o.x, o.x, fsq.x);
            fsq.y = fmaf(o.y, o.y, fsq.y);
            fsq.z = fmaf(o.z, o.z, fsq.z);
            fsq.w = fmaf(o.w, o.w, fsq.w);
        }
    }
    if (doStats) {
        float* sSum = sG;               // [8][MDIM] = 4 KB (reused)
        float* sSq  = sG + 8 * MDIM;    // [8][MDIM] = 4 KB (reused)
        *(float4*)&sSum[ty * MDIM + f0] = fsum;
        *(float4*)&sSq[ty * MDIM + f0]  = fsq;
        __syncthreads();
        if (ty == 0) {
            float4 ts = fsum, tq = fsq;
            #pragma unroll
            for (int t = 1; t < 8; ++t) {
                float4 a = *(const float4*)&sSum[t * MDIM + f0];
                float4 b = *(const float4*)&sSq[t * MDIM + f0];
                ts.x += a.x; ts.y += a.y; ts.z += a.z; ts.w += a.w;
                tq.x += b.x; tq.y += b.y; tq.z += b.z; tq.w += b.w;
            }
            atomicAdd(&stats[f0 + 0], ts.x);
            atomicAdd(&stats[f0 + 1], ts.y);
            atomicAdd(&stats[f0 + 2], ts.z);
            atomicAdd(&stats[f0 + 3], ts.w);
            atomicAdd(&stats[MDIM + f0 + 0], tq.x);
            atomicAdd(&stats[MDIM + f0 + 1], tq.y);
            atomicAdd(&stats[MDIM + f0 + 2], tq.z);
            atomicAdd(&stats[MDIM + f0 + 3], tq.w);
        }
    }
}

__global__ void k_finalize(const float* __restrict__ stats, const float* __restrict__ B,
                           const float* __restrict__ bnw, const float* __restrict__ bnb,
                           float* __restrict__ Bs, float* __restrict__ cvec, int n) {
    int f = threadIdx.x;
    float inv_n = 1.f / (float)n;
    float mu = stats[f] * inv_n;
    float var = stats[MDIM + f] * inv_n - mu * mu;
    float rs = rsqrtf(var + 1e-5f);
    float sw = rs * bnw[f];
    float cv = bnb[f] - mu * sw;
    __shared__ float red[MDIM];
    for (int o = 0; o < MY; ++o) {
        float b = B[o * MDIM + f];
        Bs[o * MDIM + f] = b * sw;
        red[f] = b * cv;
        __syncthreads();
        for (int s = 64; s > 0; s >>= 1) {
            if (f < s) red[f] += red[f + s];
            __syncthreads();
        }
        if (f == 0) cvec[o] = red[0];
        __syncthreads();
    }
}

// ---------------------------------------------------------------- projection
__global__ void __launch_bounds__(256) k_project(const float* __restrict__ Y,
                                                 const float* __restrict__ Bs,
                                                 const float* __restrict__ cvec,
                                                 float* __restrict__ out, int n) {
    __shared__ float yt[16 * 129];
    __shared__ float sB[MY * 129];
    __shared__ float sc[MY];
    int tid = threadIdx.x;
    size_t rbase = (size_t)blockIdx.x * 16;
    for (int idx = tid; idx < 16 * MDIM; idx += 256) {
        int r = idx >> 7, f = idx & 127;
        yt[r * 129 + f] = Y[(rbase + r) * MDIM + f];
    }
    for (int idx = tid; idx < MY * MDIM; idx += 256) {
        int o = idx >> 7, f = idx & 127;
        sB[o * 129 + f] = Bs[idx];
    }
    if (tid < MY) sc[tid] = cvec[tid];
    __syncthreads();
    if (tid < 16 * MY) {
        int r = tid / MY, o = tid % MY;
        float acc = sc[o];
        for (int f = 0; f < MDIM; ++f)
            acc = fmaf(yt[r * 129 + f], sB[o * 129 + f], acc);
        out[(rbase + r) * MY + o] = acc;
    }
}

// ---------------------------------------------------------------- launch
extern "C" void kernel_launch(void* const* d_in, const int* in_sizes, int n_in,
                              void* d_out, int out_size, void* d_ws, size_t ws_size,
                              hipStream_t stream) {
    const float* X    = (const float*)d_in[0];
    const float* F    = (const float*)d_in[1];
    const float* B    = (const float*)d_in[2];
    const float* bnw  = (const float*)d_in[3];
    const float* bnb  = (const float*)d_in[4];
    const float* ev   = (const float*)d_in[5];
    const int*   erow = (const int*)d_in[6];
    const int*   ecol = (const int*)d_in[7];
    float* out = (float*)d_out;
    const int n = in_sizes[0] / MDIM;  // 100000
    const int E = in_sizes[5];         // 1600000

    char* w = (char*)d_ws;
    size_t off = 0;
    auto carve = [&](size_t bytes) -> void* {
        void* p = w + off;
        off += (bytes + 255) & ~(size_t)255;
        return p;
    };
    float*          Y0    = (float*)carve((size_t)n * MDIM * 4);
    float*          Ycur  = (float*)carve((size_t)n * MDIM * 4);
    float*          SY    = (float*)carve((size_t)n * MDIM * 4);
    unsigned short* Yh    = (unsigned short*)carve((size_t)n * MDIM * 2);
    float* FF        = (float*)carve(MDIM * MDIM * 4);
    float* G         = (float*)carve(MDIM * MDIM * 4);
    v2i*   rec       = (v2i*)carve((size_t)E * 8);
    int*   row_off   = (int*)carve((size_t)(n + 1) * 4);
    int*   cursor    = (int*)carve((size_t)n * 4);
    int*   cnt       = (int*)carve((size_t)n * 4);
    int*   blockSums = (int*)carve(1024 * 4);
    float* normAcc   = (float*)carve(4);
    float* stats     = (float*)carve(2 * MDIM * 4);
    float* Bs        = (float*)carve(MY * MDIM * 4);
    float* cvec      = (float*)carve(MY * 4);
    (void)ws_size;

    hipMemsetAsync(cnt, 0, (size_t)n * 4, stream);
    hipMemsetAsync(normAcc, 0, 4, stream);
    hipMemsetAsync(stats, 0, 2 * MDIM * 4, stream);

    k_transpose<<<dim3(n / 32, MDIM / 32), dim3(32, 8), 0, stream>>>(X, Y0, Yh, n);
    k_gram<<<MDIM, MDIM, 0, stream>>>(F, FF, normAcc);
    k_gnorm<<<MDIM * MDIM / 256, 256, 0, stream>>>(FF, normAcc, G);

    const int nb = (n + 1023) / 1024;
    k_hist<<<(E + 255) / 256, 256, 0, stream>>>(erow, cnt, E);
    k_scan1<<<nb, 256, 0, stream>>>(cnt, blockSums, n);
    k_scan2<<<1, 256, 0, stream>>>(blockSums, row_off, nb, n);
    k_scan3<<<nb, 256, 0, stream>>>(cnt, blockSums, row_off, cursor, n);
    k_scatter<<<(E + 255) / 256, 256, 0, stream>>>(erow, ecol, ev, cursor, rec, E);

    for (int k = 0; k < KITER; ++k) {
        k_spmm<<<(n + 7) / 8, 256, 0, stream>>>(Yh, row_off, rec, SY, n);
        int writeH = (k < KITER - 1) ? 1 : 0;
        int doStats = (k == KITER - 1) ? 1 : 0;
        k_gemm<<<n / 32, 256, 0, stream>>>(SY, G, Y0, Ycur, Yh, stats, writeH, doStats, n);
    }

    k_finalize<<<1, MDIM, 0, stream>>>(stats, B, bnw, bnb, Bs, cvec, n);
    k_project<<<n / 16, 256, 0, stream>>>(Ycur, Bs, cvec, out, n);
}